// Round 9
// baseline (258.738 us; speedup 1.0000x reference)
//
#include <hip/hip_runtime.h>
#include <hip/hip_bf16.h>
#include <cmath>

// Problem constants
#define Bc   32
#define Sc_  512
#define Hc   768
#define NHc  12
#define DHc  64
#define Mc   (Bc * Sc_)     // 16384 tokens
#define Ntot (3 * Hc)       // 2304 fused output cols (Q|K|V)

// 0.125 (1/sqrt(DH)) * log2(e): folded into Q so softmax is exp2(s)
#define QSCALE 0.18033688011112042f

typedef __attribute__((ext_vector_type(8))) short short8v;   // 8 bf16 (4 VGPRs)
typedef __attribute__((ext_vector_type(8))) unsigned short ushort8v;
typedef __attribute__((ext_vector_type(4))) float f32x4;     // MFMA acc

static __device__ __forceinline__ ushort f2b(float f) {
    __hip_bfloat16 h = __float2bfloat16(f);
    return *reinterpret_cast<ushort*>(&h);
}
static __device__ __forceinline__ ushort2 f2b2(float a, float b) {
    __hip_bfloat162 h = __float22bfloat162_rn(float2{a, b});
    return *reinterpret_cast<ushort2*>(&h);
}

// async global->LDS, 16B per lane. HW writes lane i to (wave-uniform lds)+i*16B.
static __device__ __forceinline__ void gl2lds(const ushort* g, ushort* l) {
    __builtin_amdgcn_global_load_lds(
        (const __attribute__((address_space(1))) unsigned int*)g,
        (__attribute__((address_space(3))) unsigned int*)l, 16, 0, 0);
}

// tanh(x) = 1 - 2/(exp2(2x*log2e)+1); exact at +/-inf via rcp(inf)=0
static __device__ __forceinline__ float fast_tanh(float x) {
    float e = __builtin_amdgcn_exp2f(x * 2.885390081777927f);
    return 1.0f - 2.0f * __builtin_amdgcn_rcpf(e + 1.0f);
}

// ---------------------------------------------------------------------------
// Kernel 0 (v5): W-only repack (X conversion is fused into qkv_mfma now).
//   Wt [n/128][k/8][n%128][8] bf16. 18 panels x 12 k-groups = 216 blocks.
//   Phase 1: coalesced fp32 reads -> LDS [128][68]; phase 2: contiguous writes.
// ---------------------------------------------------------------------------
__global__ __launch_bounds__(256) void pack_w(
    const float* __restrict__ Wq, const float* __restrict__ Wk,
    const float* __restrict__ Wv,
    const float* __restrict__ bq, const float* __restrict__ bk,
    const float* __restrict__ bv,
    ushort* __restrict__ Wt, float* __restrict__ bbp)
{
    const int bx = blockIdx.x;
    const int nblk = bx / 12, kcg = bx % 12;    // 18 x 12
    const int t = threadIdx.x;

    __shared__ ushort T[128][68];

    const int n0 = nblk * 128;
    const int z = n0 / Hc;
    const int nn0 = n0 - z * Hc;
    const float* W = (z == 0) ? Wq : (z == 1) ? Wk : Wv;
    const float* base = W + (size_t)nn0 * Hc;
    ushort* out = Wt + (size_t)nblk * (96 * 1024);
    const int k0 = kcg * 64;

    const int slot = t & 15, rsub = t >> 4;
    #pragma unroll
    for (int rnd = 0; rnd < 8; ++rnd) {
        int row = rnd * 16 + rsub;
        const float* p = base + (size_t)row * Hc + k0 + slot * 4;
        float4 f = *(const float4*)p;
        ushort2 h0 = f2b2(f.x, f.y);
        ushort2 h1 = f2b2(f.z, f.w);
        ushort4 u;
        u.x = h0.x; u.y = h0.y; u.z = h1.x; u.w = h1.y;
        *(ushort4*)&T[row][slot * 4] = u;
    }
    __syncthreads();

    const int row_w = t & 127, kh = t >> 7;
    #pragma unroll
    for (int rnd = 0; rnd < 4; ++rnd) {
        int kc_l = rnd * 2 + kh;
        ushort4 lo = *(const ushort4*)&T[row_w][kc_l * 8];
        ushort4 hi = *(const ushort4*)&T[row_w][kc_l * 8 + 4];
        ushort8v o;
        o[0] = lo.x; o[1] = lo.y; o[2] = lo.z; o[3] = lo.w;
        o[4] = hi.x; o[5] = hi.y; o[6] = hi.z; o[7] = hi.w;
        *(ushort8v*)&out[(size_t)(kcg * 8 + kc_l) * 1024 + row_w * 8] = o;
    }

    if (bx == 0) {
        for (int i = t; i < Ntot; i += 256) {
            int z2 = i / Hc, nn = i - z2 * Hc;
            bbp[i] = ((z2 == 0) ? bq : (z2 == 1) ? bk : bv)[nn];
        }
    }
}

// ---------------------------------------------------------------------------
// Kernel 1 (v2): fused QKV projection with in-kernel X conversion.
//   A-side: X fp32 read directly (coalesced 128B runs), cvt_pk -> bf16,
//   ds_write_b128 into chunk-major As [kc][row][8]. B-side: gl2lds from Wt.
// Epilogue layouts (per head, head stride S*DH = 32768):
//   Qb: [s][d] row-major, pre-scaled by QSCALE
//   Kt: [kb=s/64][dchunk=d/8][s%64][8]
//   Vt: [kb=s/64][keychunk=(s%64)/8][d][8]
// ---------------------------------------------------------------------------
__global__ __launch_bounds__(256) void qkv_mfma(
    const float* __restrict__ X, const ushort* __restrict__ Wt,
    const float* __restrict__ bbp,
    ushort* __restrict__ Qb, ushort* __restrict__ Kt, ushort* __restrict__ Vt)
{
    const int tid = threadIdx.x;
    const int wave = tid >> 6, lane = tid & 63;
    const int quad = lane >> 4, l16 = lane & 15;
    const int wr = wave >> 1, wc = wave & 1;
    const int m0 = blockIdx.x * 128;
    const int n0 = blockIdx.y * 128;

    __shared__ __align__(16) ushort As[4096];   // [kc 0..3][row 0..127][8]
    __shared__ __align__(16) ushort Bs[4096];

    f32x4 acc[4][4];
    #pragma unroll
    for (int i = 0; i < 4; ++i)
        #pragma unroll
        for (int j = 0; j < 4; ++j) acc[i][j] = (f32x4)(0.f);

    // A staging roles: 4 lanes per row cover 32 k, two row-halves
    const int kcA = tid & 3;            // k-chunk 0..3
    const int rowA = tid >> 2;          // 0..63
    const float* Xp = X + (size_t)m0 * Hc;

    const ushort* gB = Wt + (size_t)blockIdx.y * (96 * 1024) + wave * 1024 + lane * 8;
    ushort* lB = Bs + wave * 1024;

    for (int t = 0; t < 24; ++t) {
        // B: async global->LDS (bf16 tiled)
        const ushort* gb = gB + t * 4096;
        gl2lds(gb,       lB);
        gl2lds(gb + 512, lB + 512);

        // A: fp32 -> bf16 in-reg -> LDS (2 rows per thread)
        {
            const float* xp0 = Xp + (size_t)rowA * Hc + t * 32 + kcA * 8;
            const float* xp1 = xp0 + (size_t)64 * Hc;
            float4 f0 = *(const float4*)&xp0[0];
            float4 f1 = *(const float4*)&xp0[4];
            float4 f2 = *(const float4*)&xp1[0];
            float4 f3 = *(const float4*)&xp1[4];
            ushort2 a0 = f2b2(f0.x, f0.y), a1 = f2b2(f0.z, f0.w);
            ushort2 a2 = f2b2(f1.x, f1.y), a3 = f2b2(f1.z, f1.w);
            ushort8v u0;
            u0[0] = a0.x; u0[1] = a0.y; u0[2] = a1.x; u0[3] = a1.y;
            u0[4] = a2.x; u0[5] = a2.y; u0[6] = a3.x; u0[7] = a3.y;
            *(ushort8v*)&As[(kcA * 128 + rowA) * 8] = u0;
            ushort2 b0 = f2b2(f2.x, f2.y), b1 = f2b2(f2.z, f2.w);
            ushort2 b2 = f2b2(f3.x, f3.y), b3 = f2b2(f3.z, f3.w);
            ushort8v u1;
            u1[0] = b0.x; u1[1] = b0.y; u1[2] = b1.x; u1[3] = b1.y;
            u1[4] = b2.x; u1[5] = b2.y; u1[6] = b3.x; u1[7] = b3.y;
            *(ushort8v*)&As[(kcA * 128 + rowA + 64) * 8] = u1;
        }
        __syncthreads();

        short8v a[4], b[4];
        #pragma unroll
        for (int i = 0; i < 4; ++i)
            a[i] = *(const short8v*)&As[quad * 1024 + (wr * 64 + i * 16 + l16) * 8];
        #pragma unroll
        for (int j = 0; j < 4; ++j)
            b[j] = *(const short8v*)&Bs[quad * 1024 + (wc * 64 + j * 16 + l16) * 8];
        #pragma unroll
        for (int i = 0; i < 4; ++i)
            #pragma unroll
            for (int j = 0; j < 4; ++j)
                acc[i][j] = __builtin_amdgcn_mfma_f32_16x16x32_bf16(
                    a[i], b[j], acc[i][j], 0, 0, 0);
        __syncthreads();
    }

    // Epilogue. C layout per 16x16 tile: col=l16, row=quad*4+r.
    const int z = n0 / Hc;
    #pragma unroll
    for (int j = 0; j < 4; ++j) {
        const int n  = n0 + wc * 64 + j * 16 + l16;
        const int nn = n - z * Hc;
        const int h  = nn >> 6, d = nn & 63;
        const float bias = bbp[n];
        #pragma unroll
        for (int i = 0; i < 4; ++i) {
            const int mbase = m0 + wr * 64 + i * 16 + quad * 4;   // s = mbase + r
            const int bb = mbase >> 9;
            const int s0 = mbase & 511;
            const size_t head = (size_t)(bb * NHc + h) * (Sc_ * DHc);
            if (z == 0) {
                size_t base = head + (size_t)s0 * DHc + d;
                #pragma unroll
                for (int r = 0; r < 4; ++r)
                    Qb[base + (size_t)r * DHc] = f2b((acc[i][j][r] + bias) * QSCALE);
            } else if (z == 1) {
                size_t base = head + (s0 >> 6) * 4096 + (d >> 3) * 512
                            + (s0 & 63) * 8 + (d & 7);
                #pragma unroll
                for (int r = 0; r < 4; ++r)
                    Kt[base + r * 8] = f2b(acc[i][j][r] + bias);
            } else {
                size_t base = head + (s0 >> 6) * 4096 + ((s0 & 63) >> 3) * 512
                            + d * 8 + (s0 & 7);
                ushort4 o;
                o.x = f2b(acc[i][j][0] + bias);
                o.y = f2b(acc[i][j][1] + bias);
                o.z = f2b(acc[i][j][2] + bias);
                o.w = f2b(acc[i][j][3] + bias);
                *(ushort4*)&Vt[base] = o;
            }
        }
    }
}

// ---------------------------------------------------------------------------
// Kernel 2: attention (R8 structure, V loads hoisted; no forced unroll).
//   1-D grid, XCD swizzle: bid%8=head-in-group, bid>>3&3=q-tile.
// ---------------------------------------------------------------------------
__global__ __launch_bounds__(256) void attn_mfma(
    const ushort* __restrict__ Qb, const ushort* __restrict__ Kt,
    const ushort* __restrict__ Vt, float* __restrict__ out)
{
    const int bid = blockIdx.x;
    const int super = bid >> 5, l = bid & 31;
    const int head_lin = super * 8 + (l & 7);     // 0..383
    const int qt = l >> 3;                        // 0..3
    const int b = head_lin / NHc, h = head_lin % NHc;

    const int wave = threadIdx.x >> 6;
    const int lane = threadIdx.x & 63;
    const int quad = lane >> 4, l16 = lane & 15;
    const int q0 = qt * 128 + wave * 32;
    const int sw = l16 & 7;                       // XOR swizzle key

    const size_t head = (size_t)head_lin * (Sc_ * DHc);
    const ushort* __restrict__ Q = Qb + head;
    const ushort* __restrict__ K = Kt + head;
    const ushort* __restrict__ V = Vt + head;

    __shared__ __align__(16) ushort Plds[4][2][1024];   // wave-private

    short8v aq[2][2];
    #pragma unroll
    for (int u = 0; u < 2; ++u)
        #pragma unroll
        for (int hf = 0; hf < 2; ++hf)
            aq[u][hf] = *(const short8v*)
                &Q[(size_t)(q0 + u * 16 + l16) * DHc + hf * 32 + quad * 8];

    short8v ones;
    #pragma unroll
    for (int i = 0; i < 8; ++i) ones[i] = (short)0x3F80;   // bf16 1.0

    f32x4 o[2][4], rsum[2];
    #pragma unroll
    for (int u = 0; u < 2; ++u) {
        rsum[u] = (f32x4)(0.f);
        #pragma unroll
        for (int t = 0; t < 4; ++t) o[u][t] = (f32x4)(0.f);
    }

    for (int kb = 0; kb < 8; ++kb) {
        const ushort* Kb_ = K + kb * 4096;
        const ushort* Vb_ = V + kb * 4096;

        short8v kf[4][2], vf[4][2];
        #pragma unroll
        for (int t = 0; t < 4; ++t) {
            kf[t][0] = *(const short8v*)&Kb_[quad * 512 + (t * 16 + l16) * 8];
            kf[t][1] = *(const short8v*)&Kb_[(4 + quad) * 512 + (t * 16 + l16) * 8];
            vf[t][0] = *(const short8v*)&Vb_[quad * 512 + (t * 16 + l16) * 8];
            vf[t][1] = *(const short8v*)&Vb_[(4 + quad) * 512 + (t * 16 + l16) * 8];
        }

        // S^T: D[key=quad*4+r][q=l16]
        f32x4 sa[2][4];
        #pragma unroll
        for (int u = 0; u < 2; ++u)
            #pragma unroll
            for (int t = 0; t < 4; ++t) {
                f32x4 s = __builtin_amdgcn_mfma_f32_16x16x32_bf16(
                    kf[t][0], aq[u][0], (f32x4)(0.f), 0, 0, 0);
                sa[u][t] = __builtin_amdgcn_mfma_f32_16x16x32_bf16(
                    kf[t][1], aq[u][1], s, 0, 0, 0);
            }

        // p = exp2(s~), pack to bf16, stage to LDS (wave-private)
        #pragma unroll
        for (int u = 0; u < 2; ++u) {
            #pragma unroll
            for (int t = 0; t < 4; ++t) {
                float p0 = __builtin_amdgcn_exp2f(sa[u][t][0]);
                float p1 = __builtin_amdgcn_exp2f(sa[u][t][1]);
                float p2 = __builtin_amdgcn_exp2f(sa[u][t][2]);
                float p3 = __builtin_amdgcn_exp2f(sa[u][t][3]);
                ushort2 lo = f2b2(p0, p1);
                ushort2 hi = f2b2(p2, p3);
                ushort4 pk;
                pk.x = lo.x; pk.y = lo.y; pk.z = hi.x; pk.w = hi.y;
                int c = t * 2 + (quad >> 1);            // key chunk 0..7
                int addr = l16 * 64 + ((c ^ sw) * 8) + (quad & 1) * 4;
                *(ushort4*)&Plds[wave][u][addr] = pk;
            }
        }

        // P A-frags (q = l16, key chunk = hf*4+quad, swizzled)
        short8v pa[2][2];
        #pragma unroll
        for (int u = 0; u < 2; ++u) {
            pa[u][0] = *(const short8v*)&Plds[wave][u][l16 * 64 + ((quad ^ sw) * 8)];
            pa[u][1] = *(const short8v*)&Plds[wave][u][l16 * 64 + (((4 + quad) ^ sw) * 8)];
        }

        // row sums via ones-MFMA
        #pragma unroll
        for (int u = 0; u < 2; ++u) {
            rsum[u] = __builtin_amdgcn_mfma_f32_16x16x32_bf16(
                pa[u][0], ones, rsum[u], 0, 0, 0);
            rsum[u] = __builtin_amdgcn_mfma_f32_16x16x32_bf16(
                pa[u][1], ones, rsum[u], 0, 0, 0);
        }

        // PV: O[q=quad*4+r][d=l16]
        #pragma unroll
        for (int t2 = 0; t2 < 4; ++t2)
            #pragma unroll
            for (int u = 0; u < 2; ++u) {
                o[u][t2] = __builtin_amdgcn_mfma_f32_16x16x32_bf16(
                    pa[u][0], vf[t2][0], o[u][t2], 0, 0, 0);
                o[u][t2] = __builtin_amdgcn_mfma_f32_16x16x32_bf16(
                    pa[u][1], vf[t2][1], o[u][t2], 0, 0, 0);
            }
    }

    // Epilogue: normalize, tanh, store.
    #pragma unroll
    for (int u = 0; u < 2; ++u) {
        #pragma unroll
        for (int r = 0; r < 4; ++r) {
            float inv = __builtin_amdgcn_rcpf(rsum[u][r]);
            int q = q0 + u * 16 + quad * 4 + r;
            size_t base = ((size_t)b * Sc_ + q) * Hc + h * DHc;
            #pragma unroll
            for (int t2 = 0; t2 < 4; ++t2)
                out[base + t2 * 16 + l16] = fast_tanh(o[u][t2][r] * inv);
        }
    }
}

extern "C" void kernel_launch(void* const* d_in, const int* in_sizes, int n_in,
                              void* d_out, int out_size, void* d_ws, size_t ws_size,
                              hipStream_t stream) {
    const float* X  = (const float*)d_in[0];
    const float* Wq = (const float*)d_in[1];
    const float* bq = (const float*)d_in[2];
    const float* Wk = (const float*)d_in[3];
    const float* bk = (const float*)d_in[4];
    const float* Wv = (const float*)d_in[5];
    const float* bv = (const float*)d_in[6];
    float* out = (float*)d_out;

    ushort* Qb  = (ushort*)d_ws;
    ushort* Kt  = Qb + (size_t)Mc * Hc;
    ushort* Vt  = Kt + (size_t)Mc * Hc;
    ushort* Wt  = Vt + (size_t)Mc * Hc;
    float*  bbp = (float*)(Wt + (size_t)Ntot * Hc);

    pack_w<<<dim3(216), 256, 0, stream>>>(Wq, Wk, Wv, bq, bk, bv, Wt, bbp);

    dim3 g1(Mc / 128, Ntot / 128);   // 128 x 18
    qkv_mfma<<<g1, 256, 0, stream>>>(X, Wt, bbp, Qb, Kt, Vt);

    attn_mfma<<<dim3(1536), 256, 0, stream>>>(Qb, Kt, Vt, out);
}

// Round 10
// 222.931 us; speedup vs baseline: 1.1606x; 1.1606x over previous
//
#include <hip/hip_runtime.h>
#include <hip/hip_bf16.h>
#include <cmath>

// Problem constants
#define Bc   32
#define Sc_  512
#define Hc   768
#define NHc  12
#define DHc  64
#define Mc   (Bc * Sc_)     // 16384 tokens
#define Ntot (3 * Hc)       // 2304 fused output cols (Q|K|V)

// 0.125 (1/sqrt(DH)) * log2(e): folded into Q so softmax is exp2(s)
#define QSCALE 0.18033688011112042f

typedef __attribute__((ext_vector_type(8))) short short8v;   // 8 bf16 (4 VGPRs)
typedef __attribute__((ext_vector_type(8))) unsigned short ushort8v;
typedef __attribute__((ext_vector_type(4))) float f32x4;     // MFMA acc

static __device__ __forceinline__ ushort f2b(float f) {
    __hip_bfloat16 h = __float2bfloat16(f);
    return *reinterpret_cast<ushort*>(&h);
}
static __device__ __forceinline__ ushort2 f2b2(float a, float b) {
    __hip_bfloat162 h = __float22bfloat162_rn(float2{a, b});
    return *reinterpret_cast<ushort2*>(&h);
}

// async global->LDS, 16B per lane. HW writes lane i to (wave-uniform lds)+i*16B.
static __device__ __forceinline__ void gl2lds(const ushort* g, ushort* l) {
    __builtin_amdgcn_global_load_lds(
        (const __attribute__((address_space(1))) unsigned int*)g,
        (__attribute__((address_space(3))) unsigned int*)l, 16, 0, 0);
}

// tanh(x) = 1 - 2/(exp2(2x*log2e)+1); exact at +/-inf via rcp(inf)=0
static __device__ __forceinline__ float fast_tanh(float x) {
    float e = __builtin_amdgcn_exp2f(x * 2.885390081777927f);
    return 1.0f - 2.0f * __builtin_amdgcn_rcpf(e + 1.0f);
}

// ---------------------------------------------------------------------------
// Kernel 0 (R8 v4, reverted): fp32 -> bf16 tiled repack, coalesced both sides.
//   Xt [m/128][k/8][m%128][8], Wt [n/128][k/8][n%128][8].
// ---------------------------------------------------------------------------
__global__ __launch_bounds__(256) void convert_pack(
    const float* __restrict__ X,
    const float* __restrict__ Wq, const float* __restrict__ Wk,
    const float* __restrict__ Wv,
    const float* __restrict__ bq, const float* __restrict__ bk,
    const float* __restrict__ bv,
    ushort* __restrict__ Xt, ushort* __restrict__ Wt, float* __restrict__ bbp)
{
    const int bx = blockIdx.x;
    const int panel = bx / 12, kcg = bx % 12;   // kcg = 64-k group
    const int t = threadIdx.x;

    __shared__ ushort T[128][68];

    const float* base;
    ushort* out;
    if (panel < 128) {
        base = X + (size_t)panel * 128 * Hc;
        out  = Xt + (size_t)panel * (96 * 1024);
    } else {
        int nblk = panel - 128;                 // 0..17
        int n0 = nblk * 128;
        int z = n0 / Hc;
        int nn0 = n0 - z * Hc;
        const float* W = (z == 0) ? Wq : (z == 1) ? Wk : Wv;
        base = W + (size_t)nn0 * Hc;
        out  = Wt + (size_t)nblk * (96 * 1024);
    }
    const int k0 = kcg * 64;

    const int slot = t & 15, rsub = t >> 4;
    #pragma unroll
    for (int rnd = 0; rnd < 8; ++rnd) {
        int row = rnd * 16 + rsub;
        const float* p = base + (size_t)row * Hc + k0 + slot * 4;
        float4 f = *(const float4*)p;
        ushort2 h0 = f2b2(f.x, f.y);
        ushort2 h1 = f2b2(f.z, f.w);
        ushort4 u;
        u.x = h0.x; u.y = h0.y; u.z = h1.x; u.w = h1.y;
        *(ushort4*)&T[row][slot * 4] = u;
    }
    __syncthreads();

    const int row_w = t & 127, kh = t >> 7;
    #pragma unroll
    for (int rnd = 0; rnd < 4; ++rnd) {
        int kc_l = rnd * 2 + kh;
        ushort4 lo = *(const ushort4*)&T[row_w][kc_l * 8];
        ushort4 hi = *(const ushort4*)&T[row_w][kc_l * 8 + 4];
        ushort8v o;
        o[0] = lo.x; o[1] = lo.y; o[2] = lo.z; o[3] = lo.w;
        o[4] = hi.x; o[5] = hi.y; o[6] = hi.z; o[7] = hi.w;
        *(ushort8v*)&out[(size_t)(kcg * 8 + kc_l) * 1024 + row_w * 8] = o;
    }

    if (bx == 0) {
        for (int i = t; i < Ntot; i += 256) {
            int z2 = i / Hc, nn = i - z2 * Hc;
            bbp[i] = ((z2 == 0) ? bq : (z2 == 1) ? bk : bv)[nn];
        }
    }
}

// ---------------------------------------------------------------------------
// Kernel 1 (R8, reverted): fused QKV projection, bf16 MFMA, gl2lds both sides.
// Epilogue layouts (per head, head stride S*DH = 32768):
//   Qb: [s][d] row-major, pre-scaled by QSCALE
//   Kt: [kb=s/64][dchunk=d/8][s%64][8]
//   Vt: [kb=s/64][keychunk=(s%64)/8][d][8]
// ---------------------------------------------------------------------------
__global__ __launch_bounds__(256) void qkv_mfma(
    const ushort* __restrict__ Xt, const ushort* __restrict__ Wt,
    const float* __restrict__ bbp,
    ushort* __restrict__ Qb, ushort* __restrict__ Kt, ushort* __restrict__ Vt)
{
    const int tid = threadIdx.x;
    const int wave = tid >> 6, lane = tid & 63;
    const int quad = lane >> 4, l16 = lane & 15;
    const int wr = wave >> 1, wc = wave & 1;
    const int m0 = blockIdx.x * 128;
    const int n0 = blockIdx.y * 128;

    __shared__ __align__(16) ushort As[4096];
    __shared__ __align__(16) ushort Bs[4096];

    f32x4 acc[4][4];
    #pragma unroll
    for (int i = 0; i < 4; ++i)
        #pragma unroll
        for (int j = 0; j < 4; ++j) acc[i][j] = (f32x4)(0.f);

    const ushort* gA = Xt + (size_t)blockIdx.x * (96 * 1024) + wave * 1024 + lane * 8;
    const ushort* gB = Wt + (size_t)blockIdx.y * (96 * 1024) + wave * 1024 + lane * 8;
    ushort* lA = As + wave * 1024;
    ushort* lB = Bs + wave * 1024;

    for (int t = 0; t < 24; ++t) {
        const ushort* ga = gA + t * 4096;
        const ushort* gb = gB + t * 4096;
        gl2lds(ga,       lA);
        gl2lds(ga + 512, lA + 512);
        gl2lds(gb,       lB);
        gl2lds(gb + 512, lB + 512);
        __syncthreads();

        short8v a[4], b[4];
        #pragma unroll
        for (int i = 0; i < 4; ++i)
            a[i] = *(const short8v*)&As[quad * 1024 + (wr * 64 + i * 16 + l16) * 8];
        #pragma unroll
        for (int j = 0; j < 4; ++j)
            b[j] = *(const short8v*)&Bs[quad * 1024 + (wc * 64 + j * 16 + l16) * 8];
        #pragma unroll
        for (int i = 0; i < 4; ++i)
            #pragma unroll
            for (int j = 0; j < 4; ++j)
                acc[i][j] = __builtin_amdgcn_mfma_f32_16x16x32_bf16(
                    a[i], b[j], acc[i][j], 0, 0, 0);
        __syncthreads();
    }

    // Epilogue. C layout per 16x16 tile: col=l16, row=quad*4+r.
    const int z = n0 / Hc;
    #pragma unroll
    for (int j = 0; j < 4; ++j) {
        const int n  = n0 + wc * 64 + j * 16 + l16;
        const int nn = n - z * Hc;
        const int h  = nn >> 6, d = nn & 63;
        const float bias = bbp[n];
        #pragma unroll
        for (int i = 0; i < 4; ++i) {
            const int mbase = m0 + wr * 64 + i * 16 + quad * 4;   // s = mbase + r
            const int bb = mbase >> 9;
            const int s0 = mbase & 511;
            const size_t head = (size_t)(bb * NHc + h) * (Sc_ * DHc);
            if (z == 0) {
                size_t base = head + (size_t)s0 * DHc + d;
                #pragma unroll
                for (int r = 0; r < 4; ++r)
                    Qb[base + (size_t)r * DHc] = f2b((acc[i][j][r] + bias) * QSCALE);
            } else if (z == 1) {
                size_t base = head + (s0 >> 6) * 4096 + (d >> 3) * 512
                            + (s0 & 63) * 8 + (d & 7);
                #pragma unroll
                for (int r = 0; r < 4; ++r)
                    Kt[base + r * 8] = f2b(acc[i][j][r] + bias);
            } else {
                size_t base = head + (s0 >> 6) * 4096 + ((s0 & 63) >> 3) * 512
                            + d * 8 + (s0 & 7);
                ushort4 o;
                o.x = f2b(acc[i][j][0] + bias);
                o.y = f2b(acc[i][j][1] + bias);
                o.z = f2b(acc[i][j][2] + bias);
                o.w = f2b(acc[i][j][3] + bias);
                *(ushort4*)&Vt[base] = o;
            }
        }
    }
}

// ---------------------------------------------------------------------------
// Kernel 2 (v5): attention, 256 q per block (wave = 64 q = 4 u-tiles).
//   2 blocks/head -> K/V logical traffic halved vs 4 blocks/head.
//   Swizzle: l=bid&15 -> head-in-group = l&7 (XCD), q-half = l>>3; both
//   blocks of a head land on the same XCD, adjacent dispatch slots.
//   kf/vf global frags loaded once per kb, shared across the 4 u-tiles.
// ---------------------------------------------------------------------------
__global__ __launch_bounds__(256, 2) void attn_mfma(
    const ushort* __restrict__ Qb, const ushort* __restrict__ Kt,
    const ushort* __restrict__ Vt, float* __restrict__ out)
{
    const int bid = blockIdx.x;
    const int super = bid >> 4, l = bid & 15;
    const int head_lin = super * 8 + (l & 7);     // 0..383
    const int qhalf = l >> 3;                     // 0..1
    const int b = head_lin / NHc, h = head_lin % NHc;

    const int wave = threadIdx.x >> 6;
    const int lane = threadIdx.x & 63;
    const int quad = lane >> 4, l16 = lane & 15;
    const int q0 = qhalf * 256 + wave * 64;       // wave owns q0..q0+63
    const int sw = l16 & 7;                       // XOR swizzle key

    const size_t head = (size_t)head_lin * (Sc_ * DHc);
    const ushort* __restrict__ Q = Qb + head;
    const ushort* __restrict__ K = Kt + head;
    const ushort* __restrict__ V = Vt + head;

    __shared__ __align__(16) ushort Plds[4][1024];   // wave-private, reused per utile

    short8v aq[4][2];
    #pragma unroll
    for (int u = 0; u < 4; ++u)
        #pragma unroll
        for (int hf = 0; hf < 2; ++hf)
            aq[u][hf] = *(const short8v*)
                &Q[(size_t)(q0 + u * 16 + l16) * DHc + hf * 32 + quad * 8];

    short8v ones;
    #pragma unroll
    for (int i = 0; i < 8; ++i) ones[i] = (short)0x3F80;   // bf16 1.0

    f32x4 o[4][4], rsum[4];
    #pragma unroll
    for (int u = 0; u < 4; ++u) {
        rsum[u] = (f32x4)(0.f);
        #pragma unroll
        for (int t = 0; t < 4; ++t) o[u][t] = (f32x4)(0.f);
    }

    for (int kb = 0; kb < 8; ++kb) {
        const ushort* Kb_ = K + kb * 4096;
        const ushort* Vb_ = V + kb * 4096;

        // K/V fragments, shared by all 4 u-tiles of this wave
        short8v kf[4][2], vf[4][2];
        #pragma unroll
        for (int t = 0; t < 4; ++t) {
            kf[t][0] = *(const short8v*)&Kb_[quad * 512 + (t * 16 + l16) * 8];
            kf[t][1] = *(const short8v*)&Kb_[(4 + quad) * 512 + (t * 16 + l16) * 8];
            vf[t][0] = *(const short8v*)&Vb_[quad * 512 + (t * 16 + l16) * 8];
            vf[t][1] = *(const short8v*)&Vb_[(4 + quad) * 512 + (t * 16 + l16) * 8];
        }

        #pragma unroll
        for (int u = 0; u < 4; ++u) {
            // S^T: D[key=quad*4+r][q=l16]
            f32x4 sa[4];
            #pragma unroll
            for (int t = 0; t < 4; ++t) {
                f32x4 s = __builtin_amdgcn_mfma_f32_16x16x32_bf16(
                    kf[t][0], aq[u][0], (f32x4)(0.f), 0, 0, 0);
                sa[t] = __builtin_amdgcn_mfma_f32_16x16x32_bf16(
                    kf[t][1], aq[u][1], s, 0, 0, 0);
            }

            // p = exp2(s~), pack to bf16, stage to LDS (wave-private)
            #pragma unroll
            for (int t = 0; t < 4; ++t) {
                float p0 = __builtin_amdgcn_exp2f(sa[t][0]);
                float p1 = __builtin_amdgcn_exp2f(sa[t][1]);
                float p2 = __builtin_amdgcn_exp2f(sa[t][2]);
                float p3 = __builtin_amdgcn_exp2f(sa[t][3]);
                ushort2 lo = f2b2(p0, p1);
                ushort2 hi = f2b2(p2, p3);
                ushort4 pk;
                pk.x = lo.x; pk.y = lo.y; pk.z = hi.x; pk.w = hi.y;
                int c = t * 2 + (quad >> 1);            // key chunk 0..7
                int addr = l16 * 64 + ((c ^ sw) * 8) + (quad & 1) * 4;
                *(ushort4*)&Plds[wave][addr] = pk;
            }

            // P A-frags (q = l16, key chunk = hf*4+quad, swizzled)
            short8v pa0 = *(const short8v*)&Plds[wave][l16 * 64 + ((quad ^ sw) * 8)];
            short8v pa1 = *(const short8v*)&Plds[wave][l16 * 64 + (((4 + quad) ^ sw) * 8)];

            // row sums via ones-MFMA
            rsum[u] = __builtin_amdgcn_mfma_f32_16x16x32_bf16(
                pa0, ones, rsum[u], 0, 0, 0);
            rsum[u] = __builtin_amdgcn_mfma_f32_16x16x32_bf16(
                pa1, ones, rsum[u], 0, 0, 0);

            // PV: O[q=quad*4+r][d=l16]
            #pragma unroll
            for (int t2 = 0; t2 < 4; ++t2) {
                o[u][t2] = __builtin_amdgcn_mfma_f32_16x16x32_bf16(
                    pa0, vf[t2][0], o[u][t2], 0, 0, 0);
                o[u][t2] = __builtin_amdgcn_mfma_f32_16x16x32_bf16(
                    pa1, vf[t2][1], o[u][t2], 0, 0, 0);
            }
        }
    }

    // Epilogue: normalize, tanh, store.
    #pragma unroll
    for (int u = 0; u < 4; ++u) {
        #pragma unroll
        for (int r = 0; r < 4; ++r) {
            float inv = __builtin_amdgcn_rcpf(rsum[u][r]);
            int q = q0 + u * 16 + quad * 4 + r;
            size_t base = ((size_t)b * Sc_ + q) * Hc + h * DHc;
            #pragma unroll
            for (int t2 = 0; t2 < 4; ++t2)
                out[base + t2 * 16 + l16] = fast_tanh(o[u][t2][r] * inv);
        }
    }
}

extern "C" void kernel_launch(void* const* d_in, const int* in_sizes, int n_in,
                              void* d_out, int out_size, void* d_ws, size_t ws_size,
                              hipStream_t stream) {
    const float* X  = (const float*)d_in[0];
    const float* Wq = (const float*)d_in[1];
    const float* bq = (const float*)d_in[2];
    const float* Wk = (const float*)d_in[3];
    const float* bk = (const float*)d_in[4];
    const float* Wv = (const float*)d_in[5];
    const float* bv = (const float*)d_in[6];
    float* out = (float*)d_out;

    ushort* Qb  = (ushort*)d_ws;
    ushort* Kt  = Qb + (size_t)Mc * Hc;
    ushort* Vt  = Kt + (size_t)Mc * Hc;
    ushort* Xt  = Vt + (size_t)Mc * Hc;
    ushort* Wt  = Xt + (size_t)Mc * Hc;
    float*  bbp = (float*)(Wt + (size_t)Ntot * Hc);

    convert_pack<<<dim3(1752), 256, 0, stream>>>(
        X, Wq, Wk, Wv, bq, bk, bv, Xt, Wt, bbp);

    dim3 g1(Mc / 128, Ntot / 128);   // 128 x 18
    qkv_mfma<<<g1, 256, 0, stream>>>(Xt, Wt, bbp, Qb, Kt, Vt);

    attn_mfma<<<dim3(768), 256, 0, stream>>>(Qb, Kt, Vt, out);
}